// Round 5
// baseline (538.214 us; speedup 1.0000x reference)
//
#include <hip/hip_runtime.h>
#include <hip/hip_bf16.h>
#include <math.h>

// Resnet50ContextualLoss: N=4, C=256, H=W=64 (P=4096), f32 in / f32 scalar out.
// loss = mean_n -log( mean_q exp(colmax_q) + 1e-5 )
//   colmax_q = max_p [ alpha_p*S[p,q] - L_p ]
//   S[n,p,q] = <xn[n,:,p], yn[n,:,q]>  (bf16 MFMA 32x32x16, K=C=256)
// GEMM passes: 128-row strips x 4 quarters, XCD-pinned, counted-vmcnt dbuf.

namespace {
constexpr int NB = 4;
constexpr int C  = 256;
constexpr int P  = 4096;
constexpr float EPSD = 1e-5f;
constexpr float EPSL = 1e-5f;
constexpr float HB   = 0.5f;

// ws layout in float units. xnT/ynT are bf16 [n][p][c], so /2.
constexpr size_t OFF_MU    = 0;                                   // 256 f32
constexpr size_t OFF_XNT   = 256;                                 // NB*P*C bf16
constexpr size_t OFF_YNT   = OFF_XNT + (size_t)NB * P * C / 2;
constexpr size_t OFF_RMAXH = OFF_YNT + (size_t)NB * P * C / 2;    // [NB*4][P]
constexpr size_t OFF_SUMH  = OFF_RMAXH + (size_t)NB * 4 * P;      // [NB*4][P]
constexpr size_t OFF_CMAXH = OFF_SUMH + (size_t)NB * 4 * P;       // [NB*4][P]
constexpr size_t OFF_RMAX  = OFF_CMAXH + (size_t)NB * 4 * P;      // [NB][P]
constexpr size_t OFF_ALPHA = OFF_RMAX + (size_t)NB * P;
constexpr size_t OFF_LROW  = OFF_ALPHA + (size_t)NB * P;
}  // namespace

typedef __attribute__((ext_vector_type(8))) __bf16 bf16x8;
typedef __attribute__((ext_vector_type(16))) float f32x16;
typedef unsigned short u16;

__device__ __forceinline__ bf16x8 ldfrag(const u16* p) {
  return *reinterpret_cast<const bf16x8*>(p);
}
__device__ __forceinline__ void gload_lds16(const u16* g, u16* l) {
  __builtin_amdgcn_global_load_lds(
      (const __attribute__((address_space(1))) void*)g,
      (__attribute__((address_space(3))) void*)l, 16, 0, 0);
}
__device__ __forceinline__ f32x16 zero16() {
  f32x16 z;
#pragma unroll
  for (int i = 0; i < 16; ++i) z[i] = 0.f;
  return z;
}

// Stage a [64 x 256] bf16 tile (rows row0..row0+63 of src[p][c]) into LDS.
// LDS dest LINEAR (global_load_lds requirement); global SOURCE pre-swizzled
// (16B-granule ^ (row&15)); reads apply the same XOR (rule #21).
// 4 global_load_lds per thread (512 thr) = 32 KB.
__device__ __forceinline__ void stage_tile64(const u16* __restrict__ src, int row0,
                                             u16* lds, int t) {
#pragma unroll
  for (int i = 0; i < 4; ++i) {
    const int g  = i * 512 + t;          // granule 0..2047
    const int r  = g >> 5;               // tile row 0..63
    const int gs = (g & 31) ^ (r & 15);  // pre-swizzled source granule
    gload_lds16(src + (size_t)(row0 + r) * 256 + gs * 8, lds + (size_t)g * 8);
  }
}

// ---------- kernel 1: per-channel mean of y_hat over (n,h,w) ----------
__global__ void k_mu(const float* __restrict__ yh, float* __restrict__ ws) {
  const int c = blockIdx.x;
  const int t = threadIdx.x;
  float s = 0.f;
  for (int n = 0; n < NB; ++n) {
    const float* base = yh + ((size_t)(n * C + c)) * P;
    for (int p = t; p < P; p += 256) s += base[p];
  }
  __shared__ float red[256];
  red[t] = s;
  __syncthreads();
  for (int w = 128; w > 0; w >>= 1) {
    if (t < w) red[t] += red[t + w];
    __syncthreads();
  }
  if (t == 0) ws[OFF_MU + c] = red[0] * (1.0f / (NB * P));
}

// ---------- kernel 2: center + L2-normalize + transpose to bf16 [p][c] ----------
__global__ __launch_bounds__(256) void k_norm(const float* __restrict__ x,
                                              const float* __restrict__ yh,
                                              float* __restrict__ ws) {
  const int b     = blockIdx.x;
  const int arr   = b & 1;
  const int strip = (b >> 1) & 63;
  const int n     = b >> 7;
  const int t     = threadIdx.x;
  const int w     = t >> 6;
  const int l     = t & 63;

  __shared__ float mu_s[C];
  __shared__ float tile[64][257];
  __shared__ float red[4][64];
  __shared__ float invs[64];

  mu_s[t] = ws[OFF_MU + t];
  __syncthreads();

  const float* src = arr ? yh : x;
  const size_t base = ((size_t)n * C) * P + (size_t)strip * 64 + l;
  float ssq = 0.f;
  for (int cc = 0; cc < C; cc += 4) {
    const int c = cc + w;
    const float v = src[base + (size_t)c * P] - mu_s[c];
    tile[l][c] = v;
    ssq += v * v;
  }
  red[w][l] = ssq;
  __syncthreads();
  if (t < 64) invs[t] = 1.0f / sqrtf(red[0][t] + red[1][t] + red[2][t] + red[3][t]);
  __syncthreads();

  uint* dst = reinterpret_cast<uint*>(ws + (arr ? OFF_YNT : OFF_XNT));
  const int c2 = t & 127;
  const size_t drow = ((size_t)n * P + (size_t)strip * 64) * (C / 2);
  for (int it = 0; it < 32; ++it) {
    const int pl = it * 2 + (t >> 7);
    const float s  = invs[pl];
    const float v0 = tile[pl][2 * c2] * s;
    const float v1 = tile[pl][2 * c2 + 1] * s;
    const unsigned short u0 = __builtin_bit_cast(unsigned short, __float2bfloat16(v0));
    const unsigned short u1 = __builtin_bit_cast(unsigned short, __float2bfloat16(v1));
    dst[drow + (size_t)pl * (C / 2) + c2] = ((uint)u1 << 16) | u0;
  }
}

// ---------- row passes (PASS0: partial rowmax, PASS1: partial rowsumexp) ----------
// bid = strip*16 + n*4 + qpart (XCD-pinned). Block: 128 rows x 1024 q.
// 8 waves = 4 row-tiles(rt,32 rows) x 2 q-sub(ct,32 q). 16 steps of 64 q.
// Counted-vmcnt double-buffer: loads never drained to 0 inside the loop.
template <int PASS>
__global__ __launch_bounds__(512, 4) void k_row(float* __restrict__ ws) {
  const int t = threadIdx.x;
  const int wave = t >> 6, l = t & 63, l31 = l & 31, lh = l >> 5, l15 = l31 & 15;
  const int rt = wave >> 1, ct = wave & 1;
  const int bid = blockIdx.x;
  const int qpart = bid & 3, n = (bid >> 2) & 3, strip = bid >> 4;
  const int p0 = strip * 128;
  const int qbase = qpart * 1024;

  const u16* xn = reinterpret_cast<const u16*>(ws + OFF_XNT) + (size_t)n * P * C;
  const u16* yn = reinterpret_cast<const u16*>(ws + OFF_YNT) + (size_t)n * P * C;

  __shared__ __align__(16) u16 Bl[2][64 * 256];
  __shared__ float red[8][32];

  // A fragments: rows p0 + rt*32 + l31, all K=256
  const u16* Ap = xn + (size_t)(p0 + rt * 32 + l31) * 256;
  bf16x8 af[16];
#pragma unroll
  for (int ks = 0; ks < 16; ++ks) af[ks] = ldfrag(Ap + (ks * 2 + lh) * 8);

  float av[16], arm[16];
  if (PASS == 1) {
#pragma unroll
    for (int r = 0; r < 16; ++r) {
      const int row = (r & 3) + 8 * (r >> 2) + 4 * lh;
      const int p = p0 + rt * 32 + row;
      const float a_ = ws[OFF_ALPHA + (size_t)n * P + p];
      av[r]  = a_;
      arm[r] = a_ * ws[OFF_RMAX + (size_t)n * P + p];
    }
  }

  float run[16];
#pragma unroll
  for (int r = 0; r < 16; ++r) run[r] = (PASS == 0) ? -3.0e38f : 0.f;

  stage_tile64(yn, qbase, Bl[0], t);

  for (int step = 0; step < 16; ++step) {
    if (step + 1 < 16) {
      stage_tile64(yn, qbase + (step + 1) * 64, Bl[(step + 1) & 1], t);
      asm volatile("s_waitcnt vmcnt(4)" ::: "memory");  // tile `step` landed
    } else {
      asm volatile("s_waitcnt vmcnt(0)" ::: "memory");
    }
    __builtin_amdgcn_sched_barrier(0);
    __builtin_amdgcn_s_barrier();

    const u16* Brow = &Bl[step & 1][(size_t)(ct * 32 + l31) * 256];
    f32x16 a0 = zero16(), a1 = zero16();
    __builtin_amdgcn_s_setprio(1);
#pragma unroll
    for (int ks = 0; ks < 16; ks += 2) {
      a0 = __builtin_amdgcn_mfma_f32_32x32x16_bf16(
          af[ks], ldfrag(Brow + ((ks * 2 + lh) ^ l15) * 8), a0, 0, 0, 0);
      a1 = __builtin_amdgcn_mfma_f32_32x32x16_bf16(
          af[ks + 1], ldfrag(Brow + ((ks * 2 + 2 + lh) ^ l15) * 8), a1, 0, 0, 0);
    }
    __builtin_amdgcn_s_setprio(0);
    const f32x16 s0 = a0 + a1;

    if (PASS == 0) {
#pragma unroll
      for (int r = 0; r < 16; ++r) run[r] = fmaxf(run[r], s0[r]);
    } else {
#pragma unroll
      for (int r = 0; r < 16; ++r) run[r] += __expf(fmaf(av[r], s0[r], -arm[r]));
    }
    __builtin_amdgcn_sched_barrier(0);
    __builtin_amdgcn_s_barrier();  // all waves done reading Bl[step&1]
  }

  // reduce across the 32 q-lanes; rows live on (reg, lh)
#pragma unroll
  for (int m = 1; m <= 16; m <<= 1) {
#pragma unroll
    for (int r = 0; r < 16; ++r) {
      const float o = __shfl_xor(run[r], m, 64);
      run[r] = (PASS == 0) ? fmaxf(run[r], o) : (run[r] + o);
    }
  }
  if (l31 == 0) {
#pragma unroll
    for (int r = 0; r < 16; ++r)
      red[wave][(r & 3) + 8 * (r >> 2) + 4 * lh] = run[r];
  }
  __syncthreads();
  if (t < 128) {
    const int rt2 = t >> 5, row = t & 31;
    const float v0 = red[rt2 * 2][row], v1 = red[rt2 * 2 + 1][row];
    const size_t o = (size_t)(n * 4 + qpart) * P + p0 + rt2 * 32 + row;
    if (PASS == 0)
      ws[OFF_RMAXH + o] = fmaxf(v0, v1);
    else
      ws[OFF_SUMH + o] = v0 + v1;
  }
}

// ---------- combine kernels ----------
__global__ void k_alpha(float* __restrict__ ws) {
  const int i = blockIdx.x * 256 + threadIdx.x;  // 0 .. NB*P-1
  const int n = i >> 12, p = i & (P - 1);
  float rm = ws[OFF_RMAXH + (size_t)(n * 4) * P + p];
#pragma unroll
  for (int j = 1; j < 4; ++j)
    rm = fmaxf(rm, ws[OFF_RMAXH + (size_t)(n * 4 + j) * P + p]);
  ws[OFF_RMAX + (size_t)n * P + p]  = rm;
  ws[OFF_ALPHA + (size_t)n * P + p] = 1.0f / (HB * (1.0f - rm + EPSD));
}

__global__ void k_L(float* __restrict__ ws) {
  const int i = blockIdx.x * 256 + threadIdx.x;
  const int n = i >> 12, p = i & (P - 1);
  float s = 0.f;
#pragma unroll
  for (int j = 0; j < 4; ++j)
    s += ws[OFF_SUMH + (size_t)(n * 4 + j) * P + p];
  const float a_ = ws[OFF_ALPHA + (size_t)n * P + p];
  const float rm = ws[OFF_RMAX + (size_t)n * P + p];
  ws[OFF_LROW + (size_t)n * P + p] = fmaf(a_, rm, logf(s));
}

// ---------- col pass: partial colmax_q over a p-quarter ----------
// bid = qstrip*16 + n*4 + ppart. Block: 128 q x 1024 p.
__global__ __launch_bounds__(512, 4) void k_col(float* __restrict__ ws) {
  const int t = threadIdx.x;
  const int wave = t >> 6, l = t & 63, l31 = l & 31, lh = l >> 5, l15 = l31 & 15;
  const int rt = wave >> 1, ct = wave & 1;
  const int bid = blockIdx.x;
  const int ppart = bid & 3, n = (bid >> 2) & 3, qstrip = bid >> 4;
  const int q0 = qstrip * 128;
  const int pbase = ppart * 1024;

  const u16* xn = reinterpret_cast<const u16*>(ws + OFF_XNT) + (size_t)n * P * C;
  const u16* yn = reinterpret_cast<const u16*>(ws + OFF_YNT) + (size_t)n * P * C;
  const float* alp = ws + OFF_ALPHA + (size_t)n * P;
  const float* lrw = ws + OFF_LROW + (size_t)n * P;

  __shared__ __align__(16) u16 Bl[2][64 * 256];
  __shared__ float red[8][32];

  const u16* Ap = yn + (size_t)(q0 + rt * 32 + l31) * 256;
  bf16x8 af[16];
#pragma unroll
  for (int ks = 0; ks < 16; ++ks) af[ks] = ldfrag(Ap + (ks * 2 + lh) * 8);

  float run[16];
#pragma unroll
  for (int r = 0; r < 16; ++r) run[r] = -3.0e38f;

  stage_tile64(xn, pbase, Bl[0], t);

  for (int step = 0; step < 16; ++step) {
    if (step + 1 < 16) {
      stage_tile64(xn, pbase + (step + 1) * 64, Bl[(step + 1) & 1], t);
      asm volatile("s_waitcnt vmcnt(4)" ::: "memory");
    } else {
      asm volatile("s_waitcnt vmcnt(0)" ::: "memory");
    }
    __builtin_amdgcn_sched_barrier(0);
    __builtin_amdgcn_s_barrier();

    const int pc = pbase + step * 64 + ct * 32 + l31;  // this lane's p (MFMA col)
    const float a_ = alp[pc];
    const float L_ = lrw[pc];

    const u16* Brow = &Bl[step & 1][(size_t)(ct * 32 + l31) * 256];
    f32x16 a0 = zero16(), a1 = zero16();
    __builtin_amdgcn_s_setprio(1);
#pragma unroll
    for (int ks = 0; ks < 16; ks += 2) {
      a0 = __builtin_amdgcn_mfma_f32_32x32x16_bf16(
          af[ks], ldfrag(Brow + ((ks * 2 + lh) ^ l15) * 8), a0, 0, 0, 0);
      a1 = __builtin_amdgcn_mfma_f32_32x32x16_bf16(
          af[ks + 1], ldfrag(Brow + ((ks * 2 + 2 + lh) ^ l15) * 8), a1, 0, 0, 0);
    }
    __builtin_amdgcn_s_setprio(0);
    const f32x16 s0 = a0 + a1;
#pragma unroll
    for (int r = 0; r < 16; ++r) run[r] = fmaxf(run[r], fmaf(a_, s0[r], -L_));

    __builtin_amdgcn_sched_barrier(0);
    __builtin_amdgcn_s_barrier();
  }

  // max over the 32 p-lanes; q rows live on (reg, lh)
#pragma unroll
  for (int m = 1; m <= 16; m <<= 1) {
#pragma unroll
    for (int r = 0; r < 16; ++r) run[r] = fmaxf(run[r], __shfl_xor(run[r], m, 64));
  }
  if (l31 == 0) {
#pragma unroll
    for (int r = 0; r < 16; ++r)
      red[wave][(r & 3) + 8 * (r >> 2) + 4 * lh] = run[r];
  }
  __syncthreads();
  if (t < 128) {
    const int rt2 = t >> 5, row = t & 31;
    const float v = fmaxf(red[rt2 * 2][row], red[rt2 * 2 + 1][row]);
    ws[OFF_CMAXH + (size_t)(n * 4 + ppart) * P + q0 + rt2 * 32 + row] = v;
  }
}

// ---------- final scalar ----------
__global__ void k_final(const float* __restrict__ ws, float* __restrict__ out) {
  const int t = threadIdx.x;  // 256
  __shared__ float red[256];
  __shared__ float lsum_s;
  if (t == 0) lsum_s = 0.f;
  for (int n = 0; n < NB; ++n) {
    float e = 0.f;
    for (int q = t; q < P; q += 256) {
      float m = ws[OFF_CMAXH + (size_t)(n * 4) * P + q];
#pragma unroll
      for (int j = 1; j < 4; ++j)
        m = fmaxf(m, ws[OFF_CMAXH + (size_t)(n * 4 + j) * P + q]);
      e += __expf(m);
    }
    __syncthreads();
    red[t] = e;
    __syncthreads();
    for (int w = 128; w > 0; w >>= 1) {
      if (t < w) red[t] += red[t + w];
      __syncthreads();
    }
    if (t == 0) lsum_s += -logf(red[0] * (1.0f / P) + EPSL);
  }
  __syncthreads();
  if (t == 0) out[0] = lsum_s * 0.25f;
}

extern "C" void kernel_launch(void* const* d_in, const int* in_sizes, int n_in,
                              void* d_out, int out_size, void* d_ws, size_t ws_size,
                              hipStream_t stream) {
  const float* x  = (const float*)d_in[0];  // y      -> x in contextual_loss
  const float* yh = (const float*)d_in[1];  // y_hat  -> y in contextual_loss
  float* ws  = (float*)d_ws;
  float* out = (float*)d_out;

  k_mu<<<dim3(C), dim3(256), 0, stream>>>(yh, ws);
  k_norm<<<dim3(NB * 64 * 2), dim3(256), 0, stream>>>(x, yh, ws);
  k_row<0><<<dim3(512), dim3(512), 0, stream>>>(ws);
  k_alpha<<<dim3(NB * P / 256), dim3(256), 0, stream>>>(ws);
  k_row<1><<<dim3(512), dim3(512), 0, stream>>>(ws);
  k_L<<<dim3(NB * P / 256), dim3(256), 0, stream>>>(ws);
  k_col<<<dim3(512), dim3(512), 0, stream>>>(ws);
  k_final<<<dim3(1), dim3(256), 0, stream>>>(ws, out);
}

// Round 6
// 219.801 us; speedup vs baseline: 2.4486x; 2.4486x over previous
//
#include <hip/hip_runtime.h>
#include <hip/hip_bf16.h>
#include <math.h>

// Resnet50ContextualLoss: N=4, C=256, H=W=64 (P=4096), f32 in / f32 scalar out.
// loss = mean_n -log( mean_q exp(colmax_q) + 1e-5 )
//   colmax_q = max_p [ alpha_p*S[p,q] - L_p ]
//   S[n,p,q] = <xn[n,:,p], yn[n,:,q]>  (bf16 MFMA 32x32x16, K=C=256)
// GEMM passes: 128-row strips x 4 quarters, XCD-pinned, counted-vmcnt dbuf,
// 64x256 staged tiles (66.5 KB LDS -> 2 blocks/CU if VGPR <= 128).

namespace {
constexpr int NB = 4;
constexpr int C  = 256;
constexpr int P  = 4096;
constexpr float EPSD = 1e-5f;
constexpr float EPSL = 1e-5f;
constexpr float HB   = 0.5f;

// ws layout in float units. xnT/ynT are bf16 [n][p][c], so /2.
constexpr size_t OFF_MU    = 0;                                   // 256 f32
constexpr size_t OFF_XNT   = 256;                                 // NB*P*C bf16
constexpr size_t OFF_YNT   = OFF_XNT + (size_t)NB * P * C / 2;
constexpr size_t OFF_RMAXH = OFF_YNT + (size_t)NB * P * C / 2;    // [NB*4][P]
constexpr size_t OFF_SUMH  = OFF_RMAXH + (size_t)NB * 4 * P;      // [NB*4][P]
constexpr size_t OFF_CMAXH = OFF_SUMH + (size_t)NB * 4 * P;       // [NB*4][P]
constexpr size_t OFF_RMAX  = OFF_CMAXH + (size_t)NB * 4 * P;      // [NB][P]
constexpr size_t OFF_ALPHA = OFF_RMAX + (size_t)NB * P;
constexpr size_t OFF_LROW  = OFF_ALPHA + (size_t)NB * P;
}  // namespace

typedef __attribute__((ext_vector_type(8))) __bf16 bf16x8;
typedef __attribute__((ext_vector_type(16))) float f32x16;
typedef unsigned short u16;

__device__ __forceinline__ bf16x8 ldfrag(const u16* p) {
  return *reinterpret_cast<const bf16x8*>(p);
}
__device__ __forceinline__ void gload_lds16(const u16* g, u16* l) {
  __builtin_amdgcn_global_load_lds(
      (const __attribute__((address_space(1))) void*)g,
      (__attribute__((address_space(3))) void*)l, 16, 0, 0);
}
__device__ __forceinline__ f32x16 zero16() {
  f32x16 z;
#pragma unroll
  for (int i = 0; i < 16; ++i) z[i] = 0.f;
  return z;
}

// Stage a [64 x 256] bf16 tile (rows row0..row0+63 of src[p][c]) into LDS.
// LDS dest LINEAR (global_load_lds requirement); global SOURCE pre-swizzled
// (16B-granule ^ (row&15)); reads apply the same XOR (rule #21).
// 4 global_load_lds per thread (512 thr) = 32 KB.
__device__ __forceinline__ void stage_tile64(const u16* __restrict__ src, int row0,
                                             u16* lds, int t) {
#pragma unroll
  for (int i = 0; i < 4; ++i) {
    const int g  = i * 512 + t;          // granule 0..2047
    const int r  = g >> 5;               // tile row 0..63
    const int gs = (g & 31) ^ (r & 15);  // pre-swizzled source granule
    gload_lds16(src + (size_t)(row0 + r) * 256 + gs * 8, lds + (size_t)g * 8);
  }
}

// ---------- kernel 1: per-channel mean of y_hat over (n,h,w) ----------
__global__ void k_mu(const float* __restrict__ yh, float* __restrict__ ws) {
  const int c = blockIdx.x;
  const int t = threadIdx.x;
  float s = 0.f;
  for (int n = 0; n < NB; ++n) {
    const float* base = yh + ((size_t)(n * C + c)) * P;
    for (int p = t; p < P; p += 256) s += base[p];
  }
  __shared__ float red[256];
  red[t] = s;
  __syncthreads();
  for (int w = 128; w > 0; w >>= 1) {
    if (t < w) red[t] += red[t + w];
    __syncthreads();
  }
  if (t == 0) ws[OFF_MU + c] = red[0] * (1.0f / (NB * P));
}

// ---------- kernel 2: center + L2-normalize + transpose to bf16 [p][c] ----------
__global__ __launch_bounds__(256) void k_norm(const float* __restrict__ x,
                                              const float* __restrict__ yh,
                                              float* __restrict__ ws) {
  const int b     = blockIdx.x;
  const int arr   = b & 1;
  const int strip = (b >> 1) & 63;
  const int n     = b >> 7;
  const int t     = threadIdx.x;
  const int w     = t >> 6;
  const int l     = t & 63;

  __shared__ float mu_s[C];
  __shared__ float tile[64][257];
  __shared__ float red[4][64];
  __shared__ float invs[64];

  mu_s[t] = ws[OFF_MU + t];
  __syncthreads();

  const float* src = arr ? yh : x;
  const size_t base = ((size_t)n * C) * P + (size_t)strip * 64 + l;
  float ssq = 0.f;
  for (int cc = 0; cc < C; cc += 4) {
    const int c = cc + w;
    const float v = src[base + (size_t)c * P] - mu_s[c];
    tile[l][c] = v;
    ssq += v * v;
  }
  red[w][l] = ssq;
  __syncthreads();
  if (t < 64) invs[t] = 1.0f / sqrtf(red[0][t] + red[1][t] + red[2][t] + red[3][t]);
  __syncthreads();

  uint* dst = reinterpret_cast<uint*>(ws + (arr ? OFF_YNT : OFF_XNT));
  const int c2 = t & 127;
  const size_t drow = ((size_t)n * P + (size_t)strip * 64) * (C / 2);
  for (int it = 0; it < 32; ++it) {
    const int pl = it * 2 + (t >> 7);
    const float s  = invs[pl];
    const float v0 = tile[pl][2 * c2] * s;
    const float v1 = tile[pl][2 * c2 + 1] * s;
    const unsigned short u0 = __builtin_bit_cast(unsigned short, __float2bfloat16(v0));
    const unsigned short u1 = __builtin_bit_cast(unsigned short, __float2bfloat16(v1));
    dst[drow + (size_t)pl * (C / 2) + c2] = ((uint)u1 << 16) | u0;
  }
}

// ---------- row passes (PASS0: partial rowmax, PASS1: partial rowsumexp) ----------
// bid = strip*16 + n*4 + qpart (XCD-pinned). Block: 128 rows x 1024 q.
// 8 waves = 4 row-tiles(rt,32 rows) x 2 q-sub(ct,32 q). 16 steps of 64 q.
// Counted-vmcnt double-buffer: loads never drained to 0 inside the loop.
// NOTE: launch_bounds min-waves stays 2 — forcing 4 caps VGPR at 128 and
// spills (R5 regression: VGPR=64, 481 MB scratch FETCH). 2 blocks/CU comes
// from small LDS + natural VGPR count instead.
template <int PASS>
__global__ __launch_bounds__(512, 2) void k_row(float* __restrict__ ws) {
  const int t = threadIdx.x;
  const int wave = t >> 6, l = t & 63, l31 = l & 31, lh = l >> 5, l15 = l31 & 15;
  const int rt = wave >> 1, ct = wave & 1;
  const int bid = blockIdx.x;
  const int qpart = bid & 3, n = (bid >> 2) & 3, strip = bid >> 4;
  const int p0 = strip * 128;
  const int qbase = qpart * 1024;

  const u16* xn = reinterpret_cast<const u16*>(ws + OFF_XNT) + (size_t)n * P * C;
  const u16* yn = reinterpret_cast<const u16*>(ws + OFF_YNT) + (size_t)n * P * C;

  __shared__ __align__(16) u16 Bl[2][64 * 256];
  __shared__ float red[8][32];

  // A fragments: rows p0 + rt*32 + l31, all K=256
  const u16* Ap = xn + (size_t)(p0 + rt * 32 + l31) * 256;
  bf16x8 af[16];
#pragma unroll
  for (int ks = 0; ks < 16; ++ks) af[ks] = ldfrag(Ap + (ks * 2 + lh) * 8);

  float av[16], arm[16];
  if (PASS == 1) {
#pragma unroll
    for (int r = 0; r < 16; ++r) {
      const int row = (r & 3) + 8 * (r >> 2) + 4 * lh;
      const int p = p0 + rt * 32 + row;
      const float a_ = ws[OFF_ALPHA + (size_t)n * P + p];
      av[r]  = a_;
      arm[r] = a_ * ws[OFF_RMAX + (size_t)n * P + p];
    }
  }

  float run[16];
#pragma unroll
  for (int r = 0; r < 16; ++r) run[r] = (PASS == 0) ? -3.0e38f : 0.f;

  stage_tile64(yn, qbase, Bl[0], t);

  for (int step = 0; step < 16; ++step) {
    if (step + 1 < 16) {
      stage_tile64(yn, qbase + (step + 1) * 64, Bl[(step + 1) & 1], t);
      asm volatile("s_waitcnt vmcnt(4)" ::: "memory");  // tile `step` landed
    } else {
      asm volatile("s_waitcnt vmcnt(0)" ::: "memory");
    }
    __builtin_amdgcn_sched_barrier(0);
    __builtin_amdgcn_s_barrier();

    const u16* Brow = &Bl[step & 1][(size_t)(ct * 32 + l31) * 256];
    f32x16 a0 = zero16(), a1 = zero16();
    __builtin_amdgcn_s_setprio(1);
#pragma unroll
    for (int ks = 0; ks < 16; ks += 2) {
      a0 = __builtin_amdgcn_mfma_f32_32x32x16_bf16(
          af[ks], ldfrag(Brow + ((ks * 2 + lh) ^ l15) * 8), a0, 0, 0, 0);
      a1 = __builtin_amdgcn_mfma_f32_32x32x16_bf16(
          af[ks + 1], ldfrag(Brow + ((ks * 2 + 2 + lh) ^ l15) * 8), a1, 0, 0, 0);
    }
    __builtin_amdgcn_s_setprio(0);
    const f32x16 s0 = a0 + a1;

    if (PASS == 0) {
#pragma unroll
      for (int r = 0; r < 16; ++r) run[r] = fmaxf(run[r], s0[r]);
    } else {
#pragma unroll
      for (int r = 0; r < 16; ++r) run[r] += __expf(fmaf(av[r], s0[r], -arm[r]));
    }
    __builtin_amdgcn_sched_barrier(0);
    __builtin_amdgcn_s_barrier();  // all waves done reading Bl[step&1]
  }

  // reduce across the 32 q-lanes; rows live on (reg, lh)
#pragma unroll
  for (int m = 1; m <= 16; m <<= 1) {
#pragma unroll
    for (int r = 0; r < 16; ++r) {
      const float o = __shfl_xor(run[r], m, 64);
      run[r] = (PASS == 0) ? fmaxf(run[r], o) : (run[r] + o);
    }
  }
  if (l31 == 0) {
#pragma unroll
    for (int r = 0; r < 16; ++r)
      red[wave][(r & 3) + 8 * (r >> 2) + 4 * lh] = run[r];
  }
  __syncthreads();
  if (t < 128) {
    const int rt2 = t >> 5, row = t & 31;
    const float v0 = red[rt2 * 2][row], v1 = red[rt2 * 2 + 1][row];
    const size_t o = (size_t)(n * 4 + qpart) * P + p0 + rt2 * 32 + row;
    if (PASS == 0)
      ws[OFF_RMAXH + o] = fmaxf(v0, v1);
    else
      ws[OFF_SUMH + o] = v0 + v1;
  }
}

// ---------- combine kernels ----------
__global__ void k_alpha(float* __restrict__ ws) {
  const int i = blockIdx.x * 256 + threadIdx.x;  // 0 .. NB*P-1
  const int n = i >> 12, p = i & (P - 1);
  float rm = ws[OFF_RMAXH + (size_t)(n * 4) * P + p];
#pragma unroll
  for (int j = 1; j < 4; ++j)
    rm = fmaxf(rm, ws[OFF_RMAXH + (size_t)(n * 4 + j) * P + p]);
  ws[OFF_RMAX + (size_t)n * P + p]  = rm;
  ws[OFF_ALPHA + (size_t)n * P + p] = 1.0f / (HB * (1.0f - rm + EPSD));
}

__global__ void k_L(float* __restrict__ ws) {
  const int i = blockIdx.x * 256 + threadIdx.x;
  const int n = i >> 12, p = i & (P - 1);
  float s = 0.f;
#pragma unroll
  for (int j = 0; j < 4; ++j)
    s += ws[OFF_SUMH + (size_t)(n * 4 + j) * P + p];
  const float a_ = ws[OFF_ALPHA + (size_t)n * P + p];
  const float rm = ws[OFF_RMAX + (size_t)n * P + p];
  ws[OFF_LROW + (size_t)n * P + p] = fmaf(a_, rm, logf(s));
}

// ---------- col pass: partial colmax_q over a p-quarter ----------
// bid = qstrip*16 + n*4 + ppart. Block: 128 q x 1024 p.
__global__ __launch_bounds__(512, 2) void k_col(float* __restrict__ ws) {
  const int t = threadIdx.x;
  const int wave = t >> 6, l = t & 63, l31 = l & 31, lh = l >> 5, l15 = l31 & 15;
  const int rt = wave >> 1, ct = wave & 1;
  const int bid = blockIdx.x;
  const int ppart = bid & 3, n = (bid >> 2) & 3, qstrip = bid >> 4;
  const int q0 = qstrip * 128;
  const int pbase = ppart * 1024;

  const u16* xn = reinterpret_cast<const u16*>(ws + OFF_XNT) + (size_t)n * P * C;
  const u16* yn = reinterpret_cast<const u16*>(ws + OFF_YNT) + (size_t)n * P * C;
  const float* alp = ws + OFF_ALPHA + (size_t)n * P;
  const float* lrw = ws + OFF_LROW + (size_t)n * P;

  __shared__ __align__(16) u16 Bl[2][64 * 256];
  __shared__ float red[8][32];

  const u16* Ap = yn + (size_t)(q0 + rt * 32 + l31) * 256;
  bf16x8 af[16];
#pragma unroll
  for (int ks = 0; ks < 16; ++ks) af[ks] = ldfrag(Ap + (ks * 2 + lh) * 8);

  float run[16];
#pragma unroll
  for (int r = 0; r < 16; ++r) run[r] = -3.0e38f;

  stage_tile64(xn, pbase, Bl[0], t);

  for (int step = 0; step < 16; ++step) {
    if (step + 1 < 16) {
      stage_tile64(xn, pbase + (step + 1) * 64, Bl[(step + 1) & 1], t);
      asm volatile("s_waitcnt vmcnt(4)" ::: "memory");
    } else {
      asm volatile("s_waitcnt vmcnt(0)" ::: "memory");
    }
    __builtin_amdgcn_sched_barrier(0);
    __builtin_amdgcn_s_barrier();

    const int pc = pbase + step * 64 + ct * 32 + l31;  // this lane's p (MFMA col)
    const float a_ = alp[pc];
    const float L_ = lrw[pc];

    const u16* Brow = &Bl[step & 1][(size_t)(ct * 32 + l31) * 256];
    f32x16 a0 = zero16(), a1 = zero16();
    __builtin_amdgcn_s_setprio(1);
#pragma unroll
    for (int ks = 0; ks < 16; ks += 2) {
      a0 = __builtin_amdgcn_mfma_f32_32x32x16_bf16(
          af[ks], ldfrag(Brow + ((ks * 2 + lh) ^ l15) * 8), a0, 0, 0, 0);
      a1 = __builtin_amdgcn_mfma_f32_32x32x16_bf16(
          af[ks + 1], ldfrag(Brow + ((ks * 2 + 2 + lh) ^ l15) * 8), a1, 0, 0, 0);
    }
    __builtin_amdgcn_s_setprio(0);
    const f32x16 s0 = a0 + a1;
#pragma unroll
    for (int r = 0; r < 16; ++r) run[r] = fmaxf(run[r], fmaf(a_, s0[r], -L_));

    __builtin_amdgcn_sched_barrier(0);
    __builtin_amdgcn_s_barrier();
  }

  // max over the 32 p-lanes; q rows live on (reg, lh)
#pragma unroll
  for (int m = 1; m <= 16; m <<= 1) {
#pragma unroll
    for (int r = 0; r < 16; ++r) run[r] = fmaxf(run[r], __shfl_xor(run[r], m, 64));
  }
  if (l31 == 0) {
#pragma unroll
    for (int r = 0; r < 16; ++r)
      red[wave][(r & 3) + 8 * (r >> 2) + 4 * lh] = run[r];
  }
  __syncthreads();
  if (t < 128) {
    const int rt2 = t >> 5, row = t & 31;
    const float v = fmaxf(red[rt2 * 2][row], red[rt2 * 2 + 1][row]);
    ws[OFF_CMAXH + (size_t)(n * 4 + ppart) * P + q0 + rt2 * 32 + row] = v;
  }
}

// ---------- final scalar ----------
__global__ void k_final(const float* __restrict__ ws, float* __restrict__ out) {
  const int t = threadIdx.x;  // 256
  __shared__ float red[256];
  __shared__ float lsum_s;
  if (t == 0) lsum_s = 0.f;
  for (int n = 0; n < NB; ++n) {
    float e = 0.f;
    for (int q = t; q < P; q += 256) {
      float m = ws[OFF_CMAXH + (size_t)(n * 4) * P + q];
#pragma unroll
      for (int j = 1; j < 4; ++j)
        m = fmaxf(m, ws[OFF_CMAXH + (size_t)(n * 4 + j) * P + q]);
      e += __expf(m);
    }
    __syncthreads();
    red[t] = e;
    __syncthreads();
    for (int w = 128; w > 0; w >>= 1) {
      if (t < w) red[t] += red[t + w];
      __syncthreads();
    }
    if (t == 0) lsum_s += -logf(red[0] * (1.0f / P) + EPSL);
  }
  __syncthreads();
  if (t == 0) out[0] = lsum_s * 0.25f;
}

extern "C" void kernel_launch(void* const* d_in, const int* in_sizes, int n_in,
                              void* d_out, int out_size, void* d_ws, size_t ws_size,
                              hipStream_t stream) {
  const float* x  = (const float*)d_in[0];  // y      -> x in contextual_loss
  const float* yh = (const float*)d_in[1];  // y_hat  -> y in contextual_loss
  float* ws  = (float*)d_ws;
  float* out = (float*)d_out;

  k_mu<<<dim3(C), dim3(256), 0, stream>>>(yh, ws);
  k_norm<<<dim3(NB * 64 * 2), dim3(256), 0, stream>>>(x, yh, ws);
  k_row<0><<<dim3(512), dim3(512), 0, stream>>>(ws);
  k_alpha<<<dim3(NB * P / 256), dim3(256), 0, stream>>>(ws);
  k_row<1><<<dim3(512), dim3(512), 0, stream>>>(ws);
  k_L<<<dim3(NB * P / 256), dim3(256), 0, stream>>>(ws);
  k_col<<<dim3(512), dim3(512), 0, stream>>>(ws);
  k_final<<<dim3(1), dim3(256), 0, stream>>>(ws, out);
}

// Round 7
// 205.974 us; speedup vs baseline: 2.6130x; 1.0671x over previous
//
#include <hip/hip_runtime.h>
#include <hip/hip_bf16.h>
#include <math.h>

// Resnet50ContextualLoss: N=4, C=256, H=W=64 (P=4096), f32 in / f32 scalar out.
// loss = mean_n -log( mean_q exp(colmax_q) + 1e-5 )
//   colmax_q = max_p [ alpha_p*S[p,q] - L_p ]
//   S[n,p,q] = <xn[n,:,p], yn[n,:,q]>  (bf16 MFMA 32x32x16, K=C=256)
// 3 GEMM passes (rowmax, rowsumexp, colmax), each: 256-row blocks, A resident
// in regs (2 row-tiles/wave -> 2 MFMA per B ds_read), streamed side staged in
// LDS via global_load_lds, triple-buffered, ONE barrier/step, counted vmcnt.
// xs = alpha_p * xn (prescaled bf16) feeds pass1/colpass: MFMA emits alpha*S.

namespace {
constexpr int NB = 4;
constexpr int C  = 256;
constexpr int P  = 4096;
constexpr float EPSD = 1e-5f;
constexpr float EPSL = 1e-5f;
constexpr float HB   = 0.5f;

// ws layout in float units. bf16 arrays [n][p][c] take NB*P*C/2 floats.
constexpr size_t OFF_MU    = 0;                                   // 256 f32
constexpr size_t OFF_XNT   = 256;
constexpr size_t OFF_YNT   = OFF_XNT + (size_t)NB * P * C / 2;
constexpr size_t OFF_XS    = OFF_YNT + (size_t)NB * P * C / 2;    // alpha*xn
constexpr size_t OFF_RMAXH = OFF_XS + (size_t)NB * P * C / 2;     // [NB*4][P]
constexpr size_t OFF_SUMH  = OFF_RMAXH + (size_t)NB * 4 * P;
constexpr size_t OFF_CMAXH = OFF_SUMH + (size_t)NB * 4 * P;
constexpr size_t OFF_RMAX  = OFF_CMAXH + (size_t)NB * 4 * P;      // [NB][P]
constexpr size_t OFF_ALPHA = OFF_RMAX + (size_t)NB * P;
constexpr size_t OFF_LROW  = OFF_ALPHA + (size_t)NB * P;
}  // namespace

typedef __attribute__((ext_vector_type(8))) __bf16 bf16x8;
typedef __attribute__((ext_vector_type(16))) float f32x16;
typedef unsigned short u16;

__device__ __forceinline__ bf16x8 ldfrag(const u16* p) {
  return *reinterpret_cast<const bf16x8*>(p);
}
__device__ __forceinline__ void gload_lds16(const u16* g, u16* l) {
  __builtin_amdgcn_global_load_lds(
      (const __attribute__((address_space(1))) void*)g,
      (__attribute__((address_space(3))) void*)l, 16, 0, 0);
}
__device__ __forceinline__ f32x16 zero16() {
  f32x16 z;
#pragma unroll
  for (int i = 0; i < 16; ++i) z[i] = 0.f;
  return z;
}

// Stage a [64 x 256] bf16 tile into LDS. LDS dest LINEAR; global SOURCE
// pre-swizzled (16B-granule ^ (row&15)); reads apply the same XOR (rule #21).
__device__ __forceinline__ void stage_tile64(const u16* __restrict__ src, int row0,
                                             u16* lds, int t) {
#pragma unroll
  for (int i = 0; i < 4; ++i) {
    const int g  = i * 512 + t;          // granule 0..2047
    const int r  = g >> 5;               // tile row 0..63
    const int gs = (g & 31) ^ (r & 15);  // pre-swizzled source granule
    gload_lds16(src + (size_t)(row0 + r) * 256 + gs * 8, lds + (size_t)g * 8);
  }
}

// ---------- kernel 1: per-channel mean of y_hat over (n,h,w) ----------
__global__ void k_mu(const float* __restrict__ yh, float* __restrict__ ws) {
  const int c = blockIdx.x;
  const int t = threadIdx.x;
  float s = 0.f;
  for (int n = 0; n < NB; ++n) {
    const float* base = yh + ((size_t)(n * C + c)) * P;
    for (int p = t; p < P; p += 256) s += base[p];
  }
  __shared__ float red[256];
  red[t] = s;
  __syncthreads();
  for (int w = 128; w > 0; w >>= 1) {
    if (t < w) red[t] += red[t + w];
    __syncthreads();
  }
  if (t == 0) ws[OFF_MU + c] = red[0] * (1.0f / (NB * P));
}

// ---------- kernel 2: center + L2-normalize + transpose to bf16 [p][c] ----------
__global__ __launch_bounds__(256) void k_norm(const float* __restrict__ x,
                                              const float* __restrict__ yh,
                                              float* __restrict__ ws) {
  const int b     = blockIdx.x;
  const int arr   = b & 1;
  const int strip = (b >> 1) & 63;
  const int n     = b >> 7;
  const int t     = threadIdx.x;
  const int w     = t >> 6;
  const int l     = t & 63;

  __shared__ float mu_s[C];
  __shared__ float tile[64][257];
  __shared__ float red[4][64];
  __shared__ float invs[64];

  mu_s[t] = ws[OFF_MU + t];
  __syncthreads();

  const float* src = arr ? yh : x;
  const size_t base = ((size_t)n * C) * P + (size_t)strip * 64 + l;
  float ssq = 0.f;
  for (int cc = 0; cc < C; cc += 4) {
    const int c = cc + w;
    const float v = src[base + (size_t)c * P] - mu_s[c];
    tile[l][c] = v;
    ssq += v * v;
  }
  red[w][l] = ssq;
  __syncthreads();
  if (t < 64) invs[t] = 1.0f / sqrtf(red[0][t] + red[1][t] + red[2][t] + red[3][t]);
  __syncthreads();

  uint* dst = reinterpret_cast<uint*>(ws + (arr ? OFF_YNT : OFF_XNT));
  const int c2 = t & 127;
  const size_t drow = ((size_t)n * P + (size_t)strip * 64) * (C / 2);
  for (int it = 0; it < 32; ++it) {
    const int pl = it * 2 + (t >> 7);
    const float s  = invs[pl];
    const float v0 = tile[pl][2 * c2] * s;
    const float v1 = tile[pl][2 * c2 + 1] * s;
    const unsigned short u0 = __builtin_bit_cast(unsigned short, __float2bfloat16(v0));
    const unsigned short u1 = __builtin_bit_cast(unsigned short, __float2bfloat16(v1));
    dst[drow + (size_t)pl * (C / 2) + c2] = ((uint)u1 << 16) | u0;
  }
}

// ---------- row passes (PASS0: partial rowmax of S; PASS1: partial sumexp) ----------
// bid = strip*16 + n*4 + qp (XCD-pinned). Block: 256 rows x 1024 q.
// 8 waves = 4 rtg (64 rows = 2 row-tiles) x 2 ct (32 q). 16 steps of 64 q.
// Triple-buffer, stage AFTER the single barrier, vmcnt counted (never 0 mid-loop).
template <int PASS>
__global__ __launch_bounds__(512) void k_rows(float* __restrict__ ws) {
  const int t = threadIdx.x;
  const int wave = t >> 6, l = t & 63, l31 = l & 31, lh = l >> 5, l15 = l31 & 15;
  const int rtg = wave >> 1, ct = wave & 1;
  const int bid = blockIdx.x;
  const int qp = bid & 3, n = (bid >> 2) & 3, strip = bid >> 4;
  const int p0 = strip * 256;
  const int qbase = qp * 1024;

  const u16* A = reinterpret_cast<const u16*>(ws + (PASS == 0 ? OFF_XNT : OFF_XS)) +
                 (size_t)n * P * C;
  const u16* yn = reinterpret_cast<const u16*>(ws + OFF_YNT) + (size_t)n * P * C;

  __shared__ __align__(16) u16 Bl[3][64 * 256];
  __shared__ float red[8][64];

  // A fragments for 2 row-tiles: rows p0 + rtg*64 + {l31, 32+l31}
  const u16* Ap0 = A + (size_t)(p0 + rtg * 64 + l31) * 256;
  bf16x8 af0[16], af1[16];
#pragma unroll
  for (int ks = 0; ks < 16; ++ks) {
    af0[ks] = ldfrag(Ap0 + (ks * 2 + lh) * 8);
    af1[ks] = ldfrag(Ap0 + 32 * 256 + (ks * 2 + lh) * 8);
  }

  float arm0[16], arm1[16];
  if (PASS == 1) {
#pragma unroll
    for (int r = 0; r < 16; ++r) {
      const int row = (r & 3) + 8 * (r >> 2) + 4 * lh;
      const int pA = p0 + rtg * 64 + row;
      arm0[r] = ws[OFF_ALPHA + (size_t)n * P + pA] * ws[OFF_RMAX + (size_t)n * P + pA];
      arm1[r] = ws[OFF_ALPHA + (size_t)n * P + pA + 32] * ws[OFF_RMAX + (size_t)n * P + pA + 32];
    }
  }

  float run0[16], run1[16];
#pragma unroll
  for (int r = 0; r < 16; ++r) {
    run0[r] = (PASS == 0) ? -3.0e38f : 0.f;
    run1[r] = (PASS == 0) ? -3.0e38f : 0.f;
  }

  // prologue: 2 tiles in flight
  stage_tile64(yn, qbase, Bl[0], t);
  stage_tile64(yn, qbase + 64, Bl[1], t);

  int cur = 0;
  for (int step = 0; step < 16; ++step) {
    if (step < 15) {
      asm volatile("s_waitcnt vmcnt(4)" ::: "memory");  // tile `step` landed
    } else {
      asm volatile("s_waitcnt vmcnt(0)" ::: "memory");
    }
    __builtin_amdgcn_sched_barrier(0);
    __builtin_amdgcn_s_barrier();
    __builtin_amdgcn_sched_barrier(0);
    if (step + 2 < 16) {
      const int nb = (cur == 0) ? 2 : cur - 1;  // (cur+2)%3
      stage_tile64(yn, qbase + (step + 2) * 64, Bl[nb], t);
    }

    const u16* Brow = &Bl[cur][(size_t)(ct * 32 + l31) * 256];
    f32x16 a0 = zero16(), a1 = zero16();
    __builtin_amdgcn_s_setprio(1);
#pragma unroll
    for (int ks = 0; ks < 16; ++ks) {
      const bf16x8 bq = ldfrag(Brow + ((ks * 2 + lh) ^ l15) * 8);
      a0 = __builtin_amdgcn_mfma_f32_32x32x16_bf16(af0[ks], bq, a0, 0, 0, 0);
      a1 = __builtin_amdgcn_mfma_f32_32x32x16_bf16(af1[ks], bq, a1, 0, 0, 0);
    }
    __builtin_amdgcn_s_setprio(0);

    if (PASS == 0) {
#pragma unroll
      for (int r = 0; r < 16; ++r) {
        run0[r] = fmaxf(run0[r], a0[r]);
        run1[r] = fmaxf(run1[r], a1[r]);
      }
    } else {
#pragma unroll
      for (int r = 0; r < 16; ++r) {
        run0[r] += __expf(a0[r] - arm0[r]);
        run1[r] += __expf(a1[r] - arm1[r]);
      }
    }
    cur = (cur == 2) ? 0 : cur + 1;
  }

  // reduce across the 32 q-lanes; rows live on (reg, lh)
#pragma unroll
  for (int m = 1; m <= 16; m <<= 1) {
#pragma unroll
    for (int r = 0; r < 16; ++r) {
      const float o0 = __shfl_xor(run0[r], m, 64);
      const float o1 = __shfl_xor(run1[r], m, 64);
      run0[r] = (PASS == 0) ? fmaxf(run0[r], o0) : (run0[r] + o0);
      run1[r] = (PASS == 0) ? fmaxf(run1[r], o1) : (run1[r] + o1);
    }
  }
  if (l31 == 0) {
#pragma unroll
    for (int r = 0; r < 16; ++r) {
      const int row = (r & 3) + 8 * (r >> 2) + 4 * lh;
      red[wave][row]      = run0[r];
      red[wave][row + 32] = run1[r];
    }
  }
  __syncthreads();
  if (t < 256) {
    const int rtg2 = t >> 6, row = t & 63;
    const float v0 = red[rtg2 * 2][row], v1 = red[rtg2 * 2 + 1][row];
    const size_t o = (size_t)(n * 4 + qp) * P + p0 + rtg2 * 64 + row;
    if (PASS == 0)
      ws[OFF_RMAXH + o] = fmaxf(v0, v1);
    else
      ws[OFF_SUMH + o] = v0 + v1;
  }
}

// ---------- combine kernels ----------
__global__ void k_alpha(float* __restrict__ ws) {
  const int i = blockIdx.x * 256 + threadIdx.x;  // 0 .. NB*P-1
  const int n = i >> 12, p = i & (P - 1);
  float rm = ws[OFF_RMAXH + (size_t)(n * 4) * P + p];
#pragma unroll
  for (int j = 1; j < 4; ++j)
    rm = fmaxf(rm, ws[OFF_RMAXH + (size_t)(n * 4 + j) * P + p]);
  ws[OFF_RMAX + (size_t)n * P + p]  = rm;
  ws[OFF_ALPHA + (size_t)n * P + p] = 1.0f / (HB * (1.0f - rm + EPSD));
}

// xs[p][c] = bf16(alpha_p * xn[p][c]) — one 16B granule per thread
__global__ __launch_bounds__(256) void k_scale(float* __restrict__ ws) {
  const int g = blockIdx.x * 256 + threadIdx.x;  // granule 0..NB*P*C/8-1
  const int rowg = g >> 5;                       // global row (n*P+p)
  const int n = rowg >> 12, p = rowg & (P - 1);
  const float a = ws[OFF_ALPHA + (size_t)n * P + p];
  const uint4 v = reinterpret_cast<const uint4*>(ws + OFF_XNT)[g];
  uint4 o;
  uint* vi = (uint*)&v;
  uint* oi = (uint*)&o;
#pragma unroll
  for (int j = 0; j < 4; ++j) {
    const uint u = vi[j];
    const float f0 = __builtin_bit_cast(float, (u & 0xffffu) << 16) * a;
    const float f1 = __builtin_bit_cast(float, (u & 0xffff0000u)) * a;
    const unsigned short b0 = __builtin_bit_cast(unsigned short, __float2bfloat16(f0));
    const unsigned short b1 = __builtin_bit_cast(unsigned short, __float2bfloat16(f1));
    oi[j] = ((uint)b1 << 16) | b0;
  }
  reinterpret_cast<uint4*>(ws + OFF_XS)[g] = o;
}

__global__ void k_L(float* __restrict__ ws) {
  const int i = blockIdx.x * 256 + threadIdx.x;
  const int n = i >> 12, p = i & (P - 1);
  float s = 0.f;
#pragma unroll
  for (int j = 0; j < 4; ++j)
    s += ws[OFF_SUMH + (size_t)(n * 4 + j) * P + p];
  const float a_ = ws[OFF_ALPHA + (size_t)n * P + p];
  const float rm = ws[OFF_RMAX + (size_t)n * P + p];
  ws[OFF_LROW + (size_t)n * P + p] = fmaf(a_, rm, logf(s));
}

// ---------- col pass: partial colmax_q of (alpha*S - L) over a p-quarter ----------
// bid = qstrip*16 + n*4 + pp. Block: 256 q x 1024 p. A = yn q-rows resident;
// streams xs (already alpha-scaled) -> value = acc - L[p].
__global__ __launch_bounds__(512) void k_colp(float* __restrict__ ws) {
  const int t = threadIdx.x;
  const int wave = t >> 6, l = t & 63, l31 = l & 31, lh = l >> 5, l15 = l31 & 15;
  const int rtg = wave >> 1, ct = wave & 1;
  const int bid = blockIdx.x;
  const int pp = bid & 3, n = (bid >> 2) & 3, qstrip = bid >> 4;
  const int q0 = qstrip * 256;
  const int pbase = pp * 1024;

  const u16* yn = reinterpret_cast<const u16*>(ws + OFF_YNT) + (size_t)n * P * C;
  const u16* xs = reinterpret_cast<const u16*>(ws + OFF_XS) + (size_t)n * P * C;
  const float* lrw = ws + OFF_LROW + (size_t)n * P;

  __shared__ __align__(16) u16 Bl[3][64 * 256];
  __shared__ float red[8][64];

  const u16* Ap0 = yn + (size_t)(q0 + rtg * 64 + l31) * 256;
  bf16x8 af0[16], af1[16];
#pragma unroll
  for (int ks = 0; ks < 16; ++ks) {
    af0[ks] = ldfrag(Ap0 + (ks * 2 + lh) * 8);
    af1[ks] = ldfrag(Ap0 + 32 * 256 + (ks * 2 + lh) * 8);
  }

  float run0[16], run1[16];
#pragma unroll
  for (int r = 0; r < 16; ++r) { run0[r] = -3.0e38f; run1[r] = -3.0e38f; }

  stage_tile64(xs, pbase, Bl[0], t);
  stage_tile64(xs, pbase + 64, Bl[1], t);

  int cur = 0;
  for (int step = 0; step < 16; ++step) {
    if (step < 15) {
      asm volatile("s_waitcnt vmcnt(4)" ::: "memory");
    } else {
      asm volatile("s_waitcnt vmcnt(0)" ::: "memory");
    }
    __builtin_amdgcn_sched_barrier(0);
    __builtin_amdgcn_s_barrier();
    __builtin_amdgcn_sched_barrier(0);
    if (step + 2 < 16) {
      const int nb = (cur == 0) ? 2 : cur - 1;
      stage_tile64(xs, pbase + (step + 2) * 64, Bl[nb], t);
    }

    const float L_ = lrw[pbase + step * 64 + ct * 32 + l31];

    const u16* Brow = &Bl[cur][(size_t)(ct * 32 + l31) * 256];
    f32x16 a0 = zero16(), a1 = zero16();
    __builtin_amdgcn_s_setprio(1);
#pragma unroll
    for (int ks = 0; ks < 16; ++ks) {
      const bf16x8 bq = ldfrag(Brow + ((ks * 2 + lh) ^ l15) * 8);
      a0 = __builtin_amdgcn_mfma_f32_32x32x16_bf16(af0[ks], bq, a0, 0, 0, 0);
      a1 = __builtin_amdgcn_mfma_f32_32x32x16_bf16(af1[ks], bq, a1, 0, 0, 0);
    }
    __builtin_amdgcn_s_setprio(0);
#pragma unroll
    for (int r = 0; r < 16; ++r) {
      run0[r] = fmaxf(run0[r], a0[r] - L_);
      run1[r] = fmaxf(run1[r], a1[r] - L_);
    }
    cur = (cur == 2) ? 0 : cur + 1;
  }

  // max over the 32 p-lanes; q rows live on (reg, lh)
#pragma unroll
  for (int m = 1; m <= 16; m <<= 1) {
#pragma unroll
    for (int r = 0; r < 16; ++r) {
      run0[r] = fmaxf(run0[r], __shfl_xor(run0[r], m, 64));
      run1[r] = fmaxf(run1[r], __shfl_xor(run1[r], m, 64));
    }
  }
  if (l31 == 0) {
#pragma unroll
    for (int r = 0; r < 16; ++r) {
      const int row = (r & 3) + 8 * (r >> 2) + 4 * lh;
      red[wave][row]      = run0[r];
      red[wave][row + 32] = run1[r];
    }
  }
  __syncthreads();
  if (t < 256) {
    const int rtg2 = t >> 6, row = t & 63;
    const float v = fmaxf(red[rtg2 * 2][row], red[rtg2 * 2 + 1][row]);
    ws[OFF_CMAXH + (size_t)(n * 4 + pp) * P + q0 + rtg2 * 64 + row] = v;
  }
}

// ---------- final scalar ----------
__global__ void k_final(const float* __restrict__ ws, float* __restrict__ out) {
  const int t = threadIdx.x;  // 256
  __shared__ float red[256];
  __shared__ float lsum_s;
  if (t == 0) lsum_s = 0.f;
  for (int n = 0; n < NB; ++n) {
    float e = 0.f;
    for (int q = t; q < P; q += 256) {
      float m = ws[OFF_CMAXH + (size_t)(n * 4) * P + q];
#pragma unroll
      for (int j = 1; j < 4; ++j)
        m = fmaxf(m, ws[OFF_CMAXH + (size_t)(n * 4 + j) * P + q]);
      e += __expf(m);
    }
    __syncthreads();
    red[t] = e;
    __syncthreads();
    for (int w = 128; w > 0; w >>= 1) {
      if (t < w) red[t] += red[t + w];
      __syncthreads();
    }
    if (t == 0) lsum_s += -logf(red[0] * (1.0f / P) + EPSL);
  }
  __syncthreads();
  if (t == 0) out[0] = lsum_s * 0.25f;
}

extern "C" void kernel_launch(void* const* d_in, const int* in_sizes, int n_in,
                              void* d_out, int out_size, void* d_ws, size_t ws_size,
                              hipStream_t stream) {
  const float* x  = (const float*)d_in[0];  // y      -> x in contextual_loss
  const float* yh = (const float*)d_in[1];  // y_hat  -> y in contextual_loss
  float* ws  = (float*)d_ws;
  float* out = (float*)d_out;

  k_mu<<<dim3(C), dim3(256), 0, stream>>>(yh, ws);
  k_norm<<<dim3(NB * 64 * 2), dim3(256), 0, stream>>>(x, yh, ws);
  k_rows<0><<<dim3(256), dim3(512), 0, stream>>>(ws);
  k_alpha<<<dim3(NB * P / 256), dim3(256), 0, stream>>>(ws);
  k_scale<<<dim3(NB * P * C / 8 / 256), dim3(256), 0, stream>>>(ws);
  k_rows<1><<<dim3(256), dim3(512), 0, stream>>>(ws);
  k_L<<<dim3(NB * P / 256), dim3(256), 0, stream>>>(ws);
  k_colp<<<dim3(256), dim3(512), 0, stream>>>(ws);
  k_final<<<dim3(1), dim3(256), 0, stream>>>(ws, out);
}